// Round 3
// baseline (1510.305 us; speedup 1.0000x reference)
//
#include <hip/hip_runtime.h>
#include <math.h>

#define KB_NUM 512
#define DIMC 64
#define BSZ 32
#define TLEN 4096
#define NTOK (BSZ * TLEN)          // 131072
#define DECAY_F 0.99f
#define EPS_F 1e-5f
#define CHUNK_K 128                // codes staged in LDS per chunk (32 KB)
#define BLK 128                    // threads per block
#define TTOK 2                     // tokens per thread
#define TOK_PER_BLK (BLK * TTOK)   // 256

// output offsets (flat f32, reference return order)
#define Q_OFF    ((size_t)0)
#define IDX_OFF  ((size_t)BSZ * DIMC * TLEN)        // 8388608
#define LOSS_OFF (IDX_OFF + (size_t)NTOK)           // 8519680
#define PLEX_OFF (LOSS_OFF + 1)                     // 8519681
#define NEMB_OFF (PLEX_OFF + 1)                     // 8519682
#define NCS_OFF  (NEMB_OFF + (size_t)KB_NUM * DIMC) // 8552450
#define NEA_OFF  (NCS_OFF + (size_t)KB_NUM)         // 8552962

// ---------------------------------------------------------------------------
// Kernel 0: 0.5 * ||e_k||^2 per code  (bit-identical to passing rounds)
// ---------------------------------------------------------------------------
__global__ void vq_enorm_kernel(const float* __restrict__ emb,
                                float* __restrict__ enorm) {
    int k = blockIdx.x * blockDim.x + threadIdx.x;
    if (k < KB_NUM) {
        const float4* e = (const float4*)(emb + (size_t)k * DIMC);
        float s = 0.f;
        #pragma unroll
        for (int i = 0; i < DIMC / 4; ++i) {
            float4 v = e[i];
            s += v.x * v.x + v.y * v.y + v.z * v.z + v.w * v.w;
        }
        enorm[k] = 0.5f * s;
    }
}

// ---------------------------------------------------------------------------
// Kernel 1: per-token argmin + quantize + loss partial + segment-sum atomics
// thread = 2 tokens (t, t+BLK); block = 128 threads = 256 tokens
// grid = (TLEN/256, BSZ) = 512 blocks. Embedding chunk in LDS, float4 reads.
// ---------------------------------------------------------------------------
__global__ __launch_bounds__(BLK, 2) void vq_main_kernel(
    const float* __restrict__ z,
    const float* __restrict__ emb,
    const float* __restrict__ enorm,
    float* __restrict__ out,
    float* __restrict__ cnt,     // [R][KB_NUM]
    float* __restrict__ esum,    // [R][KB_NUM*DIMC]
    float* __restrict__ lossAcc, // [1]
    int R)
{
    __shared__ float se[CHUNK_K * DIMC];   // 32 KB embedding chunk
    __shared__ float sen[KB_NUM];          // 2 KB enorm table

    const int tid = threadIdx.x;
    const int b = blockIdx.y;
    const int t0 = blockIdx.x * TOK_PER_BLK + tid;   // token 0
    // token 1 = t0 + BLK

    // stage enorm once (128 threads x 4)
    #pragma unroll
    for (int j = 0; j < KB_NUM / BLK; ++j)
        sen[j * BLK + tid] = enorm[j * BLK + tid];

    // load both tokens' 64 channels (coalesced across lanes)
    const float* zp = z + (size_t)b * (DIMC * TLEN) + t0;
    float zr0[DIMC], zr1[DIMC];
    #pragma unroll
    for (int c = 0; c < DIMC; ++c) {
        zr0[c] = zp[(size_t)c * TLEN];
        zr1[c] = zp[(size_t)c * TLEN + BLK];
    }

    float best0 = 3.4e38f, best1 = 3.4e38f;
    int bidx0 = 0, bidx1 = 0;

    #pragma unroll 1
    for (int ch = 0; ch < KB_NUM / CHUNK_K; ++ch) {
        __syncthreads();
        // cooperative stage: 128 codes * 64 ch = 8192 f32 = 2048 float4
        const float4* src = (const float4*)(emb + (size_t)ch * CHUNK_K * DIMC);
        float4* dst = (float4*)se;
        #pragma unroll
        for (int j = 0; j < (CHUNK_K * DIMC / 4) / BLK; ++j)
            dst[j * BLK + tid] = src[j * BLK + tid];
        __syncthreads();

        #pragma unroll 1
        for (int kk = 0; kk < CHUNK_K; kk += 2) {
            const float4* __restrict__ e0 = (const float4*)(se + kk * DIMC);
            const float4* __restrict__ e1 = (const float4*)(se + (kk + 1) * DIMC);
            // acc[token][code][c%4-class], identical reduction to prior rounds
            float p00 = 0.f, p01 = 0.f, p02 = 0.f, p03 = 0.f;  // t0,k
            float q00 = 0.f, q01 = 0.f, q02 = 0.f, q03 = 0.f;  // t0,k+1
            float p10 = 0.f, p11 = 0.f, p12 = 0.f, p13 = 0.f;  // t1,k
            float q10 = 0.f, q11 = 0.f, q12 = 0.f, q13 = 0.f;  // t1,k+1
            #pragma unroll
            for (int c4 = 0; c4 < DIMC / 4; ++c4) {
                float4 ev0 = e0[c4];
                float4 ev1 = e1[c4];
                const int c = c4 * 4;
                p00 = fmaf(zr0[c    ], ev0.x, p00);
                p01 = fmaf(zr0[c + 1], ev0.y, p01);
                p02 = fmaf(zr0[c + 2], ev0.z, p02);
                p03 = fmaf(zr0[c + 3], ev0.w, p03);
                q00 = fmaf(zr0[c    ], ev1.x, q00);
                q01 = fmaf(zr0[c + 1], ev1.y, q01);
                q02 = fmaf(zr0[c + 2], ev1.z, q02);
                q03 = fmaf(zr0[c + 3], ev1.w, q03);
                p10 = fmaf(zr1[c    ], ev0.x, p10);
                p11 = fmaf(zr1[c + 1], ev0.y, p11);
                p12 = fmaf(zr1[c + 2], ev0.z, p12);
                p13 = fmaf(zr1[c + 3], ev0.w, p13);
                q10 = fmaf(zr1[c    ], ev1.x, q10);
                q11 = fmaf(zr1[c + 1], ev1.y, q11);
                q12 = fmaf(zr1[c + 2], ev1.z, q12);
                q13 = fmaf(zr1[c + 3], ev1.w, q13);
            }
            const int k = ch * CHUNK_K + kk;
            float s00 = sen[k]     - ((p00 + p01) + (p02 + p03));
            float s01 = sen[k + 1] - ((q00 + q01) + (q02 + q03));
            float s10 = sen[k]     - ((p10 + p11) + (p12 + p13));
            float s11 = sen[k + 1] - ((q10 + q11) + (q12 + q13));
            if (s00 < best0) { best0 = s00; bidx0 = k; }
            if (s01 < best0) { best0 = s01; bidx0 = k + 1; }
            if (s10 < best1) { best1 = s10; bidx1 = k; }
            if (s11 < best1) { best1 = s11; bidx1 = k + 1; }
        }
    }

    // indices output (exact small int in f32)
    out[IDX_OFF + (size_t)b * TLEN + t0]       = (float)bidx0;
    out[IDX_OFF + (size_t)b * TLEN + t0 + BLK] = (float)bidx1;

    // quantized_st = z + (q - z), matching reference rounding; loss partials
    float* qout = out + (size_t)b * (DIMC * TLEN) + t0;
    const float* __restrict__ eb0 = emb + (size_t)bidx0 * DIMC;
    const float* __restrict__ eb1 = emb + (size_t)bidx1 * DIMC;
    float lsum = 0.f;
    #pragma unroll
    for (int c = 0; c < DIMC; ++c) {
        float d0 = eb0[c] - zr0[c];
        float d1 = eb1[c] - zr1[c];
        qout[(size_t)c * TLEN]       = zr0[c] + d0;
        qout[(size_t)c * TLEN + BLK] = zr1[c] + d1;
        lsum = fmaf(d0, d0, lsum);
        lsum = fmaf(d1, d1, lsum);
    }

    // segment sums via replicated atomics
    const int r = (int)(((unsigned)(blockIdx.y * gridDim.x + blockIdx.x)) % (unsigned)R);
    atomicAdd(cnt + (size_t)r * KB_NUM + bidx0, 1.0f);
    atomicAdd(cnt + (size_t)r * KB_NUM + bidx1, 1.0f);
    float* es0 = esum + ((size_t)r * KB_NUM + bidx0) * DIMC;
    float* es1 = esum + ((size_t)r * KB_NUM + bidx1) * DIMC;
    #pragma unroll
    for (int c = 0; c < DIMC; ++c) {
        atomicAdd(es0 + c, zr0[c]);
        atomicAdd(es1 + c, zr1[c]);
    }

    // wave-reduce loss, one atomic per wave
    #pragma unroll
    for (int off = 32; off > 0; off >>= 1)
        lsum += __shfl_down(lsum, off, 64);
    if ((tid & 63) == 0) atomicAdd(lossAcc, lsum);
}

// ---------------------------------------------------------------------------
// Kernel 2: stats — new_cluster_size, n_tot, perplexity, loss
// single block of 512 threads (thread = code k)
// ---------------------------------------------------------------------------
__global__ __launch_bounds__(512) void vq_stats_kernel(
    const float* __restrict__ cluster_size,
    const float* __restrict__ cnt,
    const float* __restrict__ lossAcc,
    float* __restrict__ out,
    float* __restrict__ ntotp,   // [1] scratch
    int R)
{
    const int k = threadIdx.x;

    float n = 0.f;
    #pragma unroll 4
    for (int r = 0; r < R; ++r) n += cnt[(size_t)r * KB_NUM + k];

    float ncs = cluster_size[k] * DECAY_F + (1.0f - DECAY_F) * n;
    out[NCS_OFF + k] = ncs;

    __shared__ float red[KB_NUM];

    // n_tot = sum(new_cluster_size)
    red[k] = ncs;
    __syncthreads();
    for (int s = KB_NUM / 2; s > 0; s >>= 1) {
        if (k < s) red[k] += red[k + s];
        __syncthreads();
    }
    if (k == 0) ntotp[0] = red[0];
    __syncthreads();

    // perplexity over p = n/N
    float p = n * (1.0f / (float)NTOK);
    red[k] = p * logf(p + 1e-10f);
    __syncthreads();
    for (int s = KB_NUM / 2; s > 0; s >>= 1) {
        if (k < s) red[k] += red[k + s];
        __syncthreads();
    }
    if (k == 0) {
        out[PLEX_OFF] = expf(-red[0]);
        out[LOSS_OFF] = 0.25f * lossAcc[0] * (1.0f / (float)(BSZ * DIMC * TLEN));
    }
}

// ---------------------------------------------------------------------------
// Kernel 3: embedding update — grid = 512 blocks (one per code) x 64 threads
// ---------------------------------------------------------------------------
__global__ __launch_bounds__(64) void vq_embed_kernel(
    const float* __restrict__ embed_avg,
    const float* __restrict__ esum,
    const float* __restrict__ ntotp,
    float* __restrict__ out,
    int R)
{
    const int k = blockIdx.x;
    const int c = threadIdx.x;

    float es = 0.f;
    #pragma unroll 4
    for (int r = 0; r < R; ++r)
        es += esum[((size_t)r * KB_NUM + k) * DIMC + c];

    float nea = embed_avg[(size_t)k * DIMC + c] * DECAY_F + (1.0f - DECAY_F) * es;
    out[NEA_OFF + (size_t)k * DIMC + c] = nea;

    float ncs  = out[NCS_OFF + k];
    float ntot = ntotp[0];
    float denom = (ncs + EPS_F) / (ntot + (float)KB_NUM * EPS_F) * ntot;
    out[NEMB_OFF + (size_t)k * DIMC + c] = nea / denom;
}

// ---------------------------------------------------------------------------
extern "C" void kernel_launch(void* const* d_in, const int* in_sizes, int n_in,
                              void* d_out, int out_size, void* d_ws, size_t ws_size,
                              hipStream_t stream)
{
    const float* z            = (const float*)d_in[0];
    const float* emb          = (const float*)d_in[1];
    const float* cluster_size = (const float*)d_in[2];
    const float* embed_avg    = (const float*)d_in[3];
    float* out = (float*)d_out;

    char* ws = (char*)d_ws;
    float* lossAcc = (float*)ws;            // 1 f32
    float* ntotp   = (float*)(ws + 64);     // 1 f32
    float* enorm   = (float*)(ws + 256);    // 512 f32
    const size_t CNT_OFF = 4096;
    const size_t perR = (size_t)(KB_NUM + KB_NUM * DIMC) * sizeof(float); // 133120 B

    int R = 1;
    if (ws_size > CNT_OFF + perR)
        R = (int)((ws_size - CNT_OFF) / perR);
    if (R < 1) R = 1;
    if (R > 16) R = 16;

    float* cnt  = (float*)(ws + CNT_OFF);          // [R][KB_NUM]
    float* esum = cnt + (size_t)R * KB_NUM;        // [R][KB_NUM*DIMC]

    // zero accumulators (lossAcc + ntot + cnt + esum); enorm is fully rewritten
    hipMemsetAsync(d_ws, 0, CNT_OFF + (size_t)R * perR, stream);

    vq_enorm_kernel<<<dim3(2), dim3(256), 0, stream>>>(emb, enorm);

    dim3 grid(TLEN / TOK_PER_BLK, BSZ);   // (16, 32) = 512 blocks
    vq_main_kernel<<<grid, dim3(BLK), 0, stream>>>(z, emb, enorm, out,
                                                   cnt, esum, lossAcc, R);

    vq_stats_kernel<<<dim3(1), dim3(512), 0, stream>>>(
        cluster_size, cnt, lossAcc, out, ntotp, R);

    vq_embed_kernel<<<dim3(KB_NUM), dim3(DIMC), 0, stream>>>(
        embed_avg, esum, ntotp, out, R);
}

// Round 4
// 714.505 us; speedup vs baseline: 2.1138x; 2.1138x over previous
//
#include <hip/hip_runtime.h>
#include <math.h>

#define KB_NUM 512
#define DIMC 64
#define BSZ 32
#define TLEN 4096
#define NTOK (BSZ * TLEN)          // 131072
#define DECAY_F 0.99f
#define EPS_F 1e-5f

#define MT 64                      // tokens per block
#define KC 16                      // channels staged per k-step

// output offsets (flat f32, reference return order)
#define Q_OFF    ((size_t)0)
#define IDX_OFF  ((size_t)BSZ * DIMC * TLEN)        // 8388608
#define LOSS_OFF (IDX_OFF + (size_t)NTOK)           // 8519680
#define PLEX_OFF (LOSS_OFF + 1)                     // 8519681
#define NEMB_OFF (PLEX_OFF + 1)                     // 8519682
#define NCS_OFF  (NEMB_OFF + (size_t)KB_NUM * DIMC) // 8552450
#define NEA_OFF  (NCS_OFF + (size_t)KB_NUM)         // 8552962

// ---------------------------------------------------------------------------
// Kernel 0a: 0.5 * ||e_k||^2 per code  (bit-identical to passing rounds)
// ---------------------------------------------------------------------------
__global__ void vq_enorm_kernel(const float* __restrict__ emb,
                                float* __restrict__ enorm) {
    int k = blockIdx.x * blockDim.x + threadIdx.x;
    if (k < KB_NUM) {
        const float4* e = (const float4*)(emb + (size_t)k * DIMC);
        float s = 0.f;
        #pragma unroll
        for (int i = 0; i < DIMC / 4; ++i) {
            float4 v = e[i];
            s += v.x * v.x + v.y * v.y + v.z * v.z + v.w * v.w;
        }
        enorm[k] = 0.5f * s;
    }
}

// ---------------------------------------------------------------------------
// Kernel 0b: transpose embedding [512][64] -> embT [64][512]
// ---------------------------------------------------------------------------
__global__ void vq_transpose_kernel(const float* __restrict__ emb,
                                    float* __restrict__ embT) {
    int i = blockIdx.x * 256 + threadIdx.x;   // 0..32767
    int k = i >> 6;        // code
    int c = i & 63;        // channel
    embT[(size_t)c * KB_NUM + k] = emb[i];
}

// ---------------------------------------------------------------------------
// Kernel 1: GEMM-tiled argmin + quantize + loss + segment-sum atomics
// block = 256 thr (4 waves) = 64 tokens x 512 codes (full K)
// thread tile = 8 tokens x 16 codes; k streamed through LDS in steps of 16
// lane: cg = ln&7 (code-group), tg = ln>>3 (token-group); wave w owns
// codes w*128 + m*32 + cg*4 + j  (m=0..3, j=0..3); tokens = tg*8 + q.
// ---------------------------------------------------------------------------
__global__ __launch_bounds__(256, 2) void vq_main_kernel(
    const float* __restrict__ z,
    const float* __restrict__ emb,
    const float* __restrict__ embT,
    const float* __restrict__ enorm,
    float* __restrict__ out,
    float* __restrict__ cnt,     // [R][KB_NUM]
    float* __restrict__ esum,    // [R][KB_NUM*DIMC]
    float* __restrict__ lossAcc, // [1]
    int R)
{
    __shared__ float z_s[KC][MT];        // 4 KB
    __shared__ float e_s[KC][KB_NUM];    // 32 KB
    __shared__ float sen[KB_NUM];        // 2 KB
    __shared__ float red_v[4][MT];       // 1 KB
    __shared__ int   red_i[4][MT];       // 1 KB
    __shared__ int   fidx[MT];           // 256 B

    const int tid = threadIdx.x;
    const int w   = tid >> 6;
    const int ln  = tid & 63;
    const int cg  = ln & 7;
    const int tg  = ln >> 3;
    const int b   = blockIdx.y;
    const int tb  = blockIdx.x * MT;

    sen[tid]       = enorm[tid];
    sen[tid + 256] = enorm[tid + 256];

    float acc[8][16];
    #pragma unroll
    for (int q = 0; q < 8; ++q)
        #pragma unroll
        for (int r = 0; r < 16; ++r) acc[q][r] = 0.f;

    const float* zg = z + (size_t)b * (DIMC * TLEN) + tb;

    #pragma unroll 1
    for (int ks = 0; ks < DIMC; ks += KC) {
        __syncthreads();
        // stage z: 16 ch x 64 tok; one float4 per thread (coalesced)
        {
            int c  = tid >> 4;
            int t4 = (tid & 15) << 2;
            float4 v = *(const float4*)(zg + (size_t)(ks + c) * TLEN + t4);
            *(float4*)&z_s[c][t4] = v;
        }
        // stage e: 16 ch x 512 codes from embT (coalesced); 8 float4/thread
        #pragma unroll
        for (int m = 0; m < 8; ++m) {
            int f  = m * 256 + tid;      // float4 index 0..2047
            int kk = f >> 7;
            int c4 = f & 127;
            float4 v = *(const float4*)(embT + (size_t)(ks + kk) * KB_NUM + c4 * 4);
            *(float4*)&e_s[kk][c4 * 4] = v;
        }
        __syncthreads();

        #pragma unroll 2
        for (int kk = 0; kk < KC; ++kk) {
            float4 zf0 = *(const float4*)&z_s[kk][tg * 8];
            float4 zf1 = *(const float4*)&z_s[kk][tg * 8 + 4];
            float4 ef[4];
            #pragma unroll
            for (int m = 0; m < 4; ++m)
                ef[m] = *(const float4*)&e_s[kk][w * 128 + m * 32 + cg * 4];
            float zq[8] = {zf0.x, zf0.y, zf0.z, zf0.w,
                           zf1.x, zf1.y, zf1.z, zf1.w};
            #pragma unroll
            for (int q = 0; q < 8; ++q) {
                #pragma unroll
                for (int m = 0; m < 4; ++m) {
                    acc[q][m * 4 + 0] = fmaf(zq[q], ef[m].x, acc[q][m * 4 + 0]);
                    acc[q][m * 4 + 1] = fmaf(zq[q], ef[m].y, acc[q][m * 4 + 1]);
                    acc[q][m * 4 + 2] = fmaf(zq[q], ef[m].z, acc[q][m * 4 + 2]);
                    acc[q][m * 4 + 3] = fmaf(zq[q], ef[m].w, acc[q][m * 4 + 3]);
                }
            }
        }
    }

    // scores s = 0.5||e||^2 - z.e ; per-thread argmin over 16 codes
    float bv[8]; int bi[8];
    #pragma unroll
    for (int q = 0; q < 8; ++q) { bv[q] = 3.4e38f; bi[q] = 0; }
    #pragma unroll
    for (int m = 0; m < 4; ++m) {
        const int cbase = w * 128 + m * 32 + cg * 4;
        float4 sv = *(const float4*)&sen[cbase];
        #pragma unroll
        for (int q = 0; q < 8; ++q) {
            float s0 = sv.x - acc[q][m * 4 + 0];
            float s1 = sv.y - acc[q][m * 4 + 1];
            float s2 = sv.z - acc[q][m * 4 + 2];
            float s3 = sv.w - acc[q][m * 4 + 3];
            if (s0 < bv[q]) { bv[q] = s0; bi[q] = cbase; }
            if (s1 < bv[q]) { bv[q] = s1; bi[q] = cbase + 1; }
            if (s2 < bv[q]) { bv[q] = s2; bi[q] = cbase + 2; }
            if (s3 < bv[q]) { bv[q] = s3; bi[q] = cbase + 3; }
        }
    }
    // reduce across the 8 code-group lanes (first-min -> lower index wins ties)
    #pragma unroll
    for (int mask = 1; mask <= 4; mask <<= 1) {
        #pragma unroll
        for (int q = 0; q < 8; ++q) {
            float ov = __shfl_xor(bv[q], mask, 64);
            int   oi = __shfl_xor(bi[q], mask, 64);
            if (ov < bv[q] || (ov == bv[q] && oi < bi[q])) { bv[q] = ov; bi[q] = oi; }
        }
    }
    if (cg == 0) {
        #pragma unroll
        for (int q = 0; q < 8; ++q) {
            red_v[w][tg * 8 + q] = bv[q];
            red_i[w][tg * 8 + q] = bi[q];
        }
    }
    __syncthreads();
    if (tid < MT) {
        float v = red_v[0][tid]; int i0 = red_i[0][tid];
        #pragma unroll
        for (int ww = 1; ww < 4; ++ww) {
            float v2 = red_v[ww][tid]; int i2 = red_i[ww][tid];
            if (v2 < v || (v2 == v && i2 < i0)) { v = v2; i0 = i2; }
        }
        fidx[tid] = i0;
        out[IDX_OFF + (size_t)b * TLEN + tb + tid] = (float)i0;
    }
    __syncthreads();

    // epilogue: thread i -> token t = i/4, channel quarter cq = i%4
    const int t  = tid >> 2;
    const int cq = tid & 3;
    const int idx = fidx[t];
    const int rrep = (int)(((unsigned)(blockIdx.y * gridDim.x + blockIdx.x)) % (unsigned)R);

    const float* er = emb + (size_t)idx * DIMC + cq * 16;
    float* qo = out + (size_t)b * (DIMC * TLEN) + tb + t;
    float* es = esum + ((size_t)rrep * KB_NUM + idx) * DIMC + cq * 16;

    float lsum = 0.f;
    #pragma unroll
    for (int j = 0; j < 16; ++j) {
        int c = cq * 16 + j;
        float zv = zg[(size_t)c * TLEN + t];
        float d  = er[j] - zv;
        qo[(size_t)c * TLEN] = zv + d;     // z + (q - z), reference rounding
        lsum = fmaf(d, d, lsum);
        atomicAdd(es + j, zv);
    }
    if (cq == 0) atomicAdd(cnt + (size_t)rrep * KB_NUM + idx, 1.0f);

    #pragma unroll
    for (int off = 32; off > 0; off >>= 1)
        lsum += __shfl_down(lsum, off, 64);
    if (ln == 0) atomicAdd(lossAcc, lsum);
}

// ---------------------------------------------------------------------------
// Kernel 2: stats — new_cluster_size, n_tot, perplexity, loss
// ---------------------------------------------------------------------------
__global__ __launch_bounds__(512) void vq_stats_kernel(
    const float* __restrict__ cluster_size,
    const float* __restrict__ cnt,
    const float* __restrict__ lossAcc,
    float* __restrict__ out,
    float* __restrict__ ntotp,
    int R)
{
    const int k = threadIdx.x;

    float n = 0.f;
    #pragma unroll 4
    for (int r = 0; r < R; ++r) n += cnt[(size_t)r * KB_NUM + k];

    float ncs = cluster_size[k] * DECAY_F + (1.0f - DECAY_F) * n;
    out[NCS_OFF + k] = ncs;

    __shared__ float red[KB_NUM];

    red[k] = ncs;
    __syncthreads();
    for (int s = KB_NUM / 2; s > 0; s >>= 1) {
        if (k < s) red[k] += red[k + s];
        __syncthreads();
    }
    if (k == 0) ntotp[0] = red[0];
    __syncthreads();

    float p = n * (1.0f / (float)NTOK);
    red[k] = p * logf(p + 1e-10f);
    __syncthreads();
    for (int s = KB_NUM / 2; s > 0; s >>= 1) {
        if (k < s) red[k] += red[k + s];
        __syncthreads();
    }
    if (k == 0) {
        out[PLEX_OFF] = expf(-red[0]);
        out[LOSS_OFF] = 0.25f * lossAcc[0] * (1.0f / (float)(BSZ * DIMC * TLEN));
    }
}

// ---------------------------------------------------------------------------
// Kernel 3: embedding update — 512 blocks x 64 threads
// ---------------------------------------------------------------------------
__global__ __launch_bounds__(64) void vq_embed_kernel(
    const float* __restrict__ embed_avg,
    const float* __restrict__ esum,
    const float* __restrict__ ntotp,
    float* __restrict__ out,
    int R)
{
    const int k = blockIdx.x;
    const int c = threadIdx.x;

    float es = 0.f;
    #pragma unroll 4
    for (int r = 0; r < R; ++r)
        es += esum[((size_t)r * KB_NUM + k) * DIMC + c];

    float nea = embed_avg[(size_t)k * DIMC + c] * DECAY_F + (1.0f - DECAY_F) * es;
    out[NEA_OFF + (size_t)k * DIMC + c] = nea;

    float ncs  = out[NCS_OFF + k];
    float ntot = ntotp[0];
    float denom = (ncs + EPS_F) / (ntot + (float)KB_NUM * EPS_F) * ntot;
    out[NEMB_OFF + (size_t)k * DIMC + c] = nea / denom;
}

// ---------------------------------------------------------------------------
extern "C" void kernel_launch(void* const* d_in, const int* in_sizes, int n_in,
                              void* d_out, int out_size, void* d_ws, size_t ws_size,
                              hipStream_t stream)
{
    const float* z            = (const float*)d_in[0];
    const float* emb          = (const float*)d_in[1];
    const float* cluster_size = (const float*)d_in[2];
    const float* embed_avg    = (const float*)d_in[3];
    float* out = (float*)d_out;

    char* ws = (char*)d_ws;
    float* lossAcc = (float*)ws;             // 1 f32
    float* ntotp   = (float*)(ws + 64);      // 1 f32
    float* enorm   = (float*)(ws + 256);     // 512 f32
    float* embT    = (float*)(ws + 4096);    // 64*512 f32 = 128 KB
    const size_t CNT_OFF = 4096 + (size_t)DIMC * KB_NUM * sizeof(float); // 135168
    const size_t perR = (size_t)(KB_NUM + KB_NUM * DIMC) * sizeof(float); // 133120

    int R = 1;
    if (ws_size > CNT_OFF + perR)
        R = (int)((ws_size - CNT_OFF) / perR);
    if (R < 1) R = 1;
    if (R > 16) R = 16;

    float* cnt  = (float*)(ws + CNT_OFF);    // [R][KB_NUM]
    float* esum = cnt + (size_t)R * KB_NUM;  // [R][KB_NUM*DIMC]

    hipMemsetAsync(ws, 0, 4096, stream);                       // lossAcc, ntot
    hipMemsetAsync(ws + CNT_OFF, 0, (size_t)R * perR, stream); // cnt + esum

    vq_enorm_kernel<<<dim3(2), dim3(256), 0, stream>>>(emb, enorm);
    vq_transpose_kernel<<<dim3(KB_NUM * DIMC / 256), dim3(256), 0, stream>>>(emb, embT);

    dim3 grid(TLEN / MT, BSZ);   // (64, 32) = 2048 blocks
    vq_main_kernel<<<grid, dim3(256), 0, stream>>>(z, emb, embT, enorm, out,
                                                   cnt, esum, lossAcc, R);

    vq_stats_kernel<<<dim3(1), dim3(512), 0, stream>>>(
        cluster_size, cnt, lossAcc, out, ntotp, R);

    vq_embed_kernel<<<dim3(KB_NUM), dim3(DIMC), 0, stream>>>(
        embed_avg, esum, ntotp, out, R);
}

// Round 5
// 230.833 us; speedup vs baseline: 6.5428x; 3.0953x over previous
//
#include <hip/hip_runtime.h>
#include <math.h>

#define KB_NUM 512
#define DIMC 64
#define BSZ 32
#define TLEN 4096
#define NTOK (BSZ * TLEN)          // 131072
#define DECAY_F 0.99f
#define EPS_F 1e-5f

#define MT 64                      // tokens per block (K1)
#define KC 16                      // channels staged per k-step (K1)
#define K2_SPAN 512                // tokens per block (K2)

// output offsets (flat f32, reference return order)
#define Q_OFF    ((size_t)0)
#define IDX_OFF  ((size_t)BSZ * DIMC * TLEN)        // 8388608
#define LOSS_OFF (IDX_OFF + (size_t)NTOK)           // 8519680
#define PLEX_OFF (LOSS_OFF + 1)                     // 8519681
#define NEMB_OFF (PLEX_OFF + 1)                     // 8519682
#define NCS_OFF  (NEMB_OFF + (size_t)KB_NUM * DIMC) // 8552450
#define NEA_OFF  (NCS_OFF + (size_t)KB_NUM)         // 8552962

// ---------------------------------------------------------------------------
// Kernel 0a: 0.5 * ||e_k||^2 per code  (bit-identical to passing rounds)
// ---------------------------------------------------------------------------
__global__ void vq_enorm_kernel(const float* __restrict__ emb,
                                float* __restrict__ enorm) {
    int k = blockIdx.x * blockDim.x + threadIdx.x;
    if (k < KB_NUM) {
        const float4* e = (const float4*)(emb + (size_t)k * DIMC);
        float s = 0.f;
        #pragma unroll
        for (int i = 0; i < DIMC / 4; ++i) {
            float4 v = e[i];
            s += v.x * v.x + v.y * v.y + v.z * v.z + v.w * v.w;
        }
        enorm[k] = 0.5f * s;
    }
}

// ---------------------------------------------------------------------------
// Kernel 0b: transpose embedding [512][64] -> embT [64][512]
// ---------------------------------------------------------------------------
__global__ void vq_transpose_kernel(const float* __restrict__ emb,
                                    float* __restrict__ embT) {
    int i = blockIdx.x * 256 + threadIdx.x;   // 0..32767
    int k = i >> 6;        // code
    int c = i & 63;        // channel
    embT[(size_t)c * KB_NUM + k] = emb[i];
}

// ---------------------------------------------------------------------------
// Kernel 1: GEMM-tiled argmin + quantize + loss  (NO scatter atomics)
// block = 256 thr (4 waves) = 64 tokens x 512 codes (full K)
// thread tile = 8 tokens x 16 codes; k streamed through LDS in steps of 16
// ---------------------------------------------------------------------------
__global__ __launch_bounds__(256, 2) void vq_main_kernel(
    const float* __restrict__ z,
    const float* __restrict__ emb,
    const float* __restrict__ embT,
    const float* __restrict__ enorm,
    float* __restrict__ out,
    float* __restrict__ lossAcc) // [1]
{
    __shared__ float z_s[KC][MT];        // 4 KB
    __shared__ float e_s[KC][KB_NUM];    // 32 KB
    __shared__ float sen[KB_NUM];        // 2 KB
    __shared__ float red_v[4][MT];       // 1 KB
    __shared__ int   red_i[4][MT];       // 1 KB
    __shared__ int   fidx[MT];           // 256 B

    const int tid = threadIdx.x;
    const int w   = tid >> 6;
    const int ln  = tid & 63;
    const int cg  = ln & 7;
    const int tg  = ln >> 3;
    const int b   = blockIdx.y;
    const int tb  = blockIdx.x * MT;

    sen[tid]       = enorm[tid];
    sen[tid + 256] = enorm[tid + 256];

    float acc[8][16];
    #pragma unroll
    for (int q = 0; q < 8; ++q)
        #pragma unroll
        for (int r = 0; r < 16; ++r) acc[q][r] = 0.f;

    const float* zg = z + (size_t)b * (DIMC * TLEN) + tb;

    #pragma unroll 1
    for (int ks = 0; ks < DIMC; ks += KC) {
        __syncthreads();
        // stage z: 16 ch x 64 tok; one float4 per thread (coalesced)
        {
            int c  = tid >> 4;
            int t4 = (tid & 15) << 2;
            float4 v = *(const float4*)(zg + (size_t)(ks + c) * TLEN + t4);
            *(float4*)&z_s[c][t4] = v;
        }
        // stage e: 16 ch x 512 codes from embT (coalesced); 8 float4/thread
        #pragma unroll
        for (int m = 0; m < 8; ++m) {
            int f  = m * 256 + tid;      // float4 index 0..2047
            int kk = f >> 7;
            int c4 = f & 127;
            float4 v = *(const float4*)(embT + (size_t)(ks + kk) * KB_NUM + c4 * 4);
            *(float4*)&e_s[kk][c4 * 4] = v;
        }
        __syncthreads();

        #pragma unroll 2
        for (int kk = 0; kk < KC; ++kk) {
            float4 zf0 = *(const float4*)&z_s[kk][tg * 8];
            float4 zf1 = *(const float4*)&z_s[kk][tg * 8 + 4];
            float4 ef[4];
            #pragma unroll
            for (int m = 0; m < 4; ++m)
                ef[m] = *(const float4*)&e_s[kk][w * 128 + m * 32 + cg * 4];
            float zq[8] = {zf0.x, zf0.y, zf0.z, zf0.w,
                           zf1.x, zf1.y, zf1.z, zf1.w};
            #pragma unroll
            for (int q = 0; q < 8; ++q) {
                #pragma unroll
                for (int m = 0; m < 4; ++m) {
                    acc[q][m * 4 + 0] = fmaf(zq[q], ef[m].x, acc[q][m * 4 + 0]);
                    acc[q][m * 4 + 1] = fmaf(zq[q], ef[m].y, acc[q][m * 4 + 1]);
                    acc[q][m * 4 + 2] = fmaf(zq[q], ef[m].z, acc[q][m * 4 + 2]);
                    acc[q][m * 4 + 3] = fmaf(zq[q], ef[m].w, acc[q][m * 4 + 3]);
                }
            }
        }
    }

    // scores s = 0.5||e||^2 - z.e ; per-thread argmin over 16 codes
    float bv[8]; int bi[8];
    #pragma unroll
    for (int q = 0; q < 8; ++q) { bv[q] = 3.4e38f; bi[q] = 0; }
    #pragma unroll
    for (int m = 0; m < 4; ++m) {
        const int cbase = w * 128 + m * 32 + cg * 4;
        float4 sv = *(const float4*)&sen[cbase];
        #pragma unroll
        for (int q = 0; q < 8; ++q) {
            float s0 = sv.x - acc[q][m * 4 + 0];
            float s1 = sv.y - acc[q][m * 4 + 1];
            float s2 = sv.z - acc[q][m * 4 + 2];
            float s3 = sv.w - acc[q][m * 4 + 3];
            if (s0 < bv[q]) { bv[q] = s0; bi[q] = cbase; }
            if (s1 < bv[q]) { bv[q] = s1; bi[q] = cbase + 1; }
            if (s2 < bv[q]) { bv[q] = s2; bi[q] = cbase + 2; }
            if (s3 < bv[q]) { bv[q] = s3; bi[q] = cbase + 3; }
        }
    }
    // reduce across the 8 code-group lanes (first-min -> lower index wins ties)
    #pragma unroll
    for (int mask = 1; mask <= 4; mask <<= 1) {
        #pragma unroll
        for (int q = 0; q < 8; ++q) {
            float ov = __shfl_xor(bv[q], mask, 64);
            int   oi = __shfl_xor(bi[q], mask, 64);
            if (ov < bv[q] || (ov == bv[q] && oi < bi[q])) { bv[q] = ov; bi[q] = oi; }
        }
    }
    if (cg == 0) {
        #pragma unroll
        for (int q = 0; q < 8; ++q) {
            red_v[w][tg * 8 + q] = bv[q];
            red_i[w][tg * 8 + q] = bi[q];
        }
    }
    __syncthreads();
    if (tid < MT) {
        float v = red_v[0][tid]; int i0 = red_i[0][tid];
        #pragma unroll
        for (int ww = 1; ww < 4; ++ww) {
            float v2 = red_v[ww][tid]; int i2 = red_i[ww][tid];
            if (v2 < v || (v2 == v && i2 < i0)) { v = v2; i0 = i2; }
        }
        fidx[tid] = i0;
        out[IDX_OFF + (size_t)b * TLEN + tb + tid] = (float)i0;
    }
    __syncthreads();

    // epilogue: thread i -> token t = i/4, channel quarter cq = i%4
    const int t  = tid >> 2;
    const int cq = tid & 3;
    const int idx = fidx[t];

    const float* er = emb + (size_t)idx * DIMC + cq * 16;
    float* qo = out + (size_t)b * (DIMC * TLEN) + tb + t;

    float lsum = 0.f;
    #pragma unroll
    for (int j = 0; j < 16; ++j) {
        int c = cq * 16 + j;
        float zv = zg[(size_t)c * TLEN + t];
        float d  = er[j] - zv;
        qo[(size_t)c * TLEN] = zv + d;     // z + (q - z), reference rounding
        lsum = fmaf(d, d, lsum);
    }

    #pragma unroll
    for (int off = 32; off > 0; off >>= 1)
        lsum += __shfl_down(lsum, off, 64);
    if (ln == 0) atomicAdd(lossAcc, lsum);
}

// ---------------------------------------------------------------------------
// Kernel 2: segment-sum binning via LDS accumulator, replica-atomic flush
// grid = NTOK/K2_SPAN = 256 blocks x 256 thr; 1 block/CU (132 KB LDS)
// ---------------------------------------------------------------------------
__global__ __launch_bounds__(256, 1) void vq_bin_kernel(
    const float* __restrict__ z,
    const float* __restrict__ out,    // reads idx at IDX_OFF
    float* __restrict__ cnt,          // [R][KB_NUM]
    float* __restrict__ esum,         // [R][KB_NUM*DIMC]
    int R)
{
    __shared__ float acc[KB_NUM][DIMC + 1];   // 512*65*4 = 133120 B -> pad kills bank pile-up
    __shared__ float scnt[KB_NUM];

    const int tid = threadIdx.x;
    for (int j = tid; j < KB_NUM * (DIMC + 1); j += 256) ((float*)acc)[j] = 0.f;
    for (int j = tid; j < KB_NUM; j += 256) scnt[j] = 0.f;
    __syncthreads();

    const int gt0 = blockIdx.x * K2_SPAN;
    #pragma unroll
    for (int it = 0; it < K2_SPAN / 256; ++it) {
        const int gt = gt0 + it * 256 + tid;      // flat token id = b*TLEN + t
        const int b  = gt >> 12;                  // TLEN = 4096
        const int t  = gt & (TLEN - 1);
        const int idx = (int)out[IDX_OFF + gt];
        atomicAdd(&scnt[idx], 1.0f);
        const float* zp = z + (size_t)b * (DIMC * TLEN) + t;
        #pragma unroll 4
        for (int c = 0; c < DIMC; ++c) {
            float zv = zp[(size_t)c * TLEN];      // coalesced across lanes
            atomicAdd(&acc[idx][c], zv);          // LDS ds_add, (idx+c)%32 banks
        }
    }
    __syncthreads();

    // flush to replica r (contiguous addresses per wave -> coalesced RMW)
    const int r = (int)((unsigned)blockIdx.x % (unsigned)R);
    for (int j = tid; j < KB_NUM * DIMC; j += 256) {
        const int k = j >> 6, c = j & 63;
        float v = acc[k][c];
        if (v != 0.f) atomicAdd(esum + (size_t)r * (KB_NUM * DIMC) + j, v);
    }
    for (int j = tid; j < KB_NUM; j += 256) {
        float v = scnt[j];
        if (v != 0.f) atomicAdd(cnt + (size_t)r * KB_NUM + j, v);
    }
}

// ---------------------------------------------------------------------------
// Kernel 3: stats — new_cluster_size, n_tot, perplexity, loss
// ---------------------------------------------------------------------------
__global__ __launch_bounds__(512) void vq_stats_kernel(
    const float* __restrict__ cluster_size,
    const float* __restrict__ cnt,
    const float* __restrict__ lossAcc,
    float* __restrict__ out,
    float* __restrict__ ntotp,
    int R)
{
    const int k = threadIdx.x;

    float n = 0.f;
    #pragma unroll 4
    for (int r = 0; r < R; ++r) n += cnt[(size_t)r * KB_NUM + k];

    float ncs = cluster_size[k] * DECAY_F + (1.0f - DECAY_F) * n;
    out[NCS_OFF + k] = ncs;

    __shared__ float red[KB_NUM];

    red[k] = ncs;
    __syncthreads();
    for (int s = KB_NUM / 2; s > 0; s >>= 1) {
        if (k < s) red[k] += red[k + s];
        __syncthreads();
    }
    if (k == 0) ntotp[0] = red[0];
    __syncthreads();

    float p = n * (1.0f / (float)NTOK);
    red[k] = p * logf(p + 1e-10f);
    __syncthreads();
    for (int s = KB_NUM / 2; s > 0; s >>= 1) {
        if (k < s) red[k] += red[k + s];
        __syncthreads();
    }
    if (k == 0) {
        out[PLEX_OFF] = expf(-red[0]);
        out[LOSS_OFF] = 0.25f * lossAcc[0] * (1.0f / (float)(BSZ * DIMC * TLEN));
    }
}

// ---------------------------------------------------------------------------
// Kernel 4: embedding update — 512 blocks x 64 threads
// ---------------------------------------------------------------------------
__global__ __launch_bounds__(64) void vq_embed_kernel(
    const float* __restrict__ embed_avg,
    const float* __restrict__ esum,
    const float* __restrict__ ntotp,
    float* __restrict__ out,
    int R)
{
    const int k = blockIdx.x;
    const int c = threadIdx.x;

    float es = 0.f;
    #pragma unroll 4
    for (int r = 0; r < R; ++r)
        es += esum[((size_t)r * KB_NUM + k) * DIMC + c];

    float nea = embed_avg[(size_t)k * DIMC + c] * DECAY_F + (1.0f - DECAY_F) * es;
    out[NEA_OFF + (size_t)k * DIMC + c] = nea;

    float ncs  = out[NCS_OFF + k];
    float ntot = ntotp[0];
    float denom = (ncs + EPS_F) / (ntot + (float)KB_NUM * EPS_F) * ntot;
    out[NEMB_OFF + (size_t)k * DIMC + c] = nea / denom;
}

// ---------------------------------------------------------------------------
extern "C" void kernel_launch(void* const* d_in, const int* in_sizes, int n_in,
                              void* d_out, int out_size, void* d_ws, size_t ws_size,
                              hipStream_t stream)
{
    const float* z            = (const float*)d_in[0];
    const float* emb          = (const float*)d_in[1];
    const float* cluster_size = (const float*)d_in[2];
    const float* embed_avg    = (const float*)d_in[3];
    float* out = (float*)d_out;

    char* ws = (char*)d_ws;
    float* lossAcc = (float*)ws;             // 1 f32
    float* ntotp   = (float*)(ws + 64);      // 1 f32
    float* enorm   = (float*)(ws + 256);     // 512 f32
    float* embT    = (float*)(ws + 4096);    // 64*512 f32 = 128 KB
    const size_t CNT_OFF = 4096 + (size_t)DIMC * KB_NUM * sizeof(float); // 135168
    const size_t perR = (size_t)(KB_NUM + KB_NUM * DIMC) * sizeof(float); // 133120

    int R = 1;
    if (ws_size > CNT_OFF + perR)
        R = (int)((ws_size - CNT_OFF) / perR);
    if (R < 1) R = 1;
    if (R > 16) R = 16;

    float* cnt  = (float*)(ws + CNT_OFF);    // [R][KB_NUM]
    float* esum = cnt + (size_t)R * KB_NUM;  // [R][KB_NUM*DIMC]

    hipMemsetAsync(ws, 0, 4096, stream);                       // lossAcc, ntot
    hipMemsetAsync(ws + CNT_OFF, 0, (size_t)R * perR, stream); // cnt + esum

    vq_enorm_kernel<<<dim3(2), dim3(256), 0, stream>>>(emb, enorm);
    vq_transpose_kernel<<<dim3(KB_NUM * DIMC / 256), dim3(256), 0, stream>>>(emb, embT);

    dim3 grid(TLEN / MT, BSZ);   // (64, 32) = 2048 blocks
    vq_main_kernel<<<grid, dim3(256), 0, stream>>>(z, emb, embT, enorm, out, lossAcc);

    vq_bin_kernel<<<dim3(NTOK / K2_SPAN), dim3(256), 0, stream>>>(z, out, cnt, esum, R);

    vq_stats_kernel<<<dim3(1), dim3(512), 0, stream>>>(
        cluster_size, cnt, lossAcc, out, ntotp, R);

    vq_embed_kernel<<<dim3(KB_NUM), dim3(DIMC), 0, stream>>>(
        embed_avg, esum, ntotp, out, R);
}

// Round 6
// 153.717 us; speedup vs baseline: 9.8253x; 1.5017x over previous
//
#include <hip/hip_runtime.h>
#include <math.h>

#define KB_NUM 512
#define DIMC 64
#define BSZ 32
#define TLEN 4096
#define NTOK (BSZ * TLEN)          // 131072
#define DECAY_F 0.99f
#define EPS_F 1e-5f
#define K2_SPAN 512                // tokens per block (bin kernel)

// output offsets (flat f32, reference return order)
#define Q_OFF    ((size_t)0)
#define IDX_OFF  ((size_t)BSZ * DIMC * TLEN)        // 8388608
#define LOSS_OFF (IDX_OFF + (size_t)NTOK)           // 8519680
#define PLEX_OFF (LOSS_OFF + 1)                     // 8519681
#define NEMB_OFF (PLEX_OFF + 1)                     // 8519682
#define NCS_OFF  (NEMB_OFF + (size_t)KB_NUM * DIMC) // 8552450
#define NEA_OFF  (NCS_OFF + (size_t)KB_NUM)         // 8552962

typedef _Float16 f16x8 __attribute__((ext_vector_type(8)));
typedef float    f32x4 __attribute__((ext_vector_type(4)));

// ---------------------------------------------------------------------------
// Kernel 0: prep embedding — f16 hi/lo split + 0.5*||e||^2 (fp32)
// grid = 512 blocks x 64 threads (block = code, thread = channel)
// ---------------------------------------------------------------------------
__global__ __launch_bounds__(64) void vq_prep_e(
    const float* __restrict__ emb,
    _Float16* __restrict__ eh,
    _Float16* __restrict__ el,
    float* __restrict__ enorm)
{
    const int k = blockIdx.x;
    const int c = threadIdx.x;
    float v = emb[(size_t)k * DIMC + c];
    _Float16 h = (_Float16)v;
    eh[(size_t)k * DIMC + c] = h;
    el[(size_t)k * DIMC + c] = (_Float16)(v - (float)h);
    float s = v * v;
    #pragma unroll
    for (int off = 32; off > 0; off >>= 1)
        s += __shfl_down(s, off, 64);
    if (c == 0) enorm[k] = 0.5f * s;
}

// ---------------------------------------------------------------------------
// Kernel 1: MFMA argmin + quantize + loss
// block = 256 thr = 4 waves; block tile = 256 tokens x 512 codes.
// Wave w owns tokens [w*64, w*64+64): 4 token-tiles (N) x 32 code-tiles (M),
// K=64 split in 2 MFMA k-steps of 32. Scores via 4-term f16 hi/lo MFMA
// (exactly (zh+zl)&middot;(eh+el) in f32 accumulation = fp32-class precision).
// Fragment maps (mfma_f32_16x16x32_f16):
//   A[m][k]: m = lane&15, k = (lane>>4)*8+j   (m = code row)
//   B[k][n]: n = lane&15, k = (lane>>4)*8+j   (n = token col)
//   D:       col(n) = lane&15, row(m) = (lane>>4)*4+reg   [m89-verified]
// Same k-map on A and B => any k-permutation mismatch cancels in the dot.
// ---------------------------------------------------------------------------
__global__ __launch_bounds__(256, 2) void vq_main_kernel(
    const float* __restrict__ z,
    const float* __restrict__ emb,
    const _Float16* __restrict__ eh,
    const _Float16* __restrict__ el,
    const float* __restrict__ enorm,
    float* __restrict__ out,
    float* __restrict__ lossAcc)
{
    __shared__ float zs[256 * 65];   // [token][ch], pad 65 -> bank = tok%32 on col writes

    const int tid = threadIdx.x;
    const int w   = tid >> 6;
    const int ln  = tid & 63;
    const int bk  = blockIdx.x;
    const int b   = bk >> 4;               // 16 blocks per batch row
    const int t0  = (bk & 15) << 8;        // 256 tokens per block

    const float* zg = z + (size_t)b * (DIMC * TLEN) + t0;

    // stage: transpose z[c][t] -> zs[t][c] (f32). Global dword coalesced,
    // ds_write bank = (tid*65+c)%32 = (tid+c)%32 -> conflict-free.
    #pragma unroll 8
    for (int c = 0; c < DIMC; ++c)
        zs[tid * 65 + c] = zg[(size_t)c * TLEN + tid];
    __syncthreads();

    // build B fragments once (held in VGPRs for the whole K-loop)
    f16x8 zhf[4][2], zlf[4][2];
    #pragma unroll
    for (int tt = 0; tt < 4; ++tt) {
        #pragma unroll
        for (int ks = 0; ks < 2; ++ks) {
            const float* zrow = &zs[(w * 64 + tt * 16 + (ln & 15)) * 65
                                    + ks * 32 + ((ln >> 4) << 3)];
            #pragma unroll
            for (int j = 0; j < 8; ++j) {
                float v = zrow[j];
                _Float16 h = (_Float16)v;
                zhf[tt][ks][j] = h;
                zlf[tt][ks][j] = (_Float16)(v - (float)h);
            }
        }
    }

    float bv[4] = {3.4e38f, 3.4e38f, 3.4e38f, 3.4e38f};
    int   bi[4] = {0, 0, 0, 0};

    #pragma unroll 1
    for (int chunk = 0; chunk < 8; ++chunk) {        // 64 codes per chunk
        f32x4 acc[4][4];
        #pragma unroll
        for (int ct = 0; ct < 4; ++ct)
            #pragma unroll
            for (int tt = 0; tt < 4; ++tt)
                acc[ct][tt] = (f32x4){0.f, 0.f, 0.f, 0.f};

        #pragma unroll
        for (int ct = 0; ct < 4; ++ct) {
            const int crow = chunk * 64 + ct * 16 + (ln & 15);
            f16x8 ah[2], al[2];
            #pragma unroll
            for (int ks = 0; ks < 2; ++ks) {
                const size_t aoff = (size_t)crow * DIMC + ks * 32 + ((ln >> 4) << 3);
                ah[ks] = *(const f16x8*)(eh + aoff);
                al[ks] = *(const f16x8*)(el + aoff);
            }
            #pragma unroll
            for (int ks = 0; ks < 2; ++ks) {
                #pragma unroll
                for (int tt = 0; tt < 4; ++tt)
                    acc[ct][tt] = __builtin_amdgcn_mfma_f32_16x16x32_f16(
                        ah[ks], zhf[tt][ks], acc[ct][tt], 0, 0, 0);
                #pragma unroll
                for (int tt = 0; tt < 4; ++tt)
                    acc[ct][tt] = __builtin_amdgcn_mfma_f32_16x16x32_f16(
                        ah[ks], zlf[tt][ks], acc[ct][tt], 0, 0, 0);
                #pragma unroll
                for (int tt = 0; tt < 4; ++tt)
                    acc[ct][tt] = __builtin_amdgcn_mfma_f32_16x16x32_f16(
                        al[ks], zhf[tt][ks], acc[ct][tt], 0, 0, 0);
                #pragma unroll
                for (int tt = 0; tt < 4; ++tt)
                    acc[ct][tt] = __builtin_amdgcn_mfma_f32_16x16x32_f16(
                        al[ks], zlf[tt][ks], acc[ct][tt], 0, 0, 0);
            }
        }

        // fold: s = 0.5||e||^2 - z.e ; ascending code order (chunk, ct, reg)
        #pragma unroll
        for (int ct = 0; ct < 4; ++ct) {
            const int cb = chunk * 64 + ct * 16 + ((ln >> 4) << 2);
            float4 en = *(const float4*)(enorm + cb);
            const float e0 = en.x, e1 = en.y, e2 = en.z, e3 = en.w;
            #pragma unroll
            for (int tt = 0; tt < 4; ++tt) {
                float s0 = e0 - acc[ct][tt][0];
                float s1 = e1 - acc[ct][tt][1];
                float s2 = e2 - acc[ct][tt][2];
                float s3 = e3 - acc[ct][tt][3];
                if (s0 < bv[tt]) { bv[tt] = s0; bi[tt] = cb; }
                if (s1 < bv[tt]) { bv[tt] = s1; bi[tt] = cb + 1; }
                if (s2 < bv[tt]) { bv[tt] = s2; bi[tt] = cb + 2; }
                if (s3 < bv[tt]) { bv[tt] = s3; bi[tt] = cb + 3; }
            }
        }
    }

    // cross-lane fold over the 4 row-groups (lane>>4); lower index wins ties
    #pragma unroll
    for (int mask = 16; mask <= 32; mask <<= 1) {
        #pragma unroll
        for (int tt = 0; tt < 4; ++tt) {
            float ov = __shfl_xor(bv[tt], mask, 64);
            int   oi = __shfl_xor(bi[tt], mask, 64);
            if (ov < bv[tt] || (ov == bv[tt] && oi < bi[tt])) {
                bv[tt] = ov; bi[tt] = oi;
            }
        }
    }

    // epilogue: lane ln owns token w*64 + ln = (ln>>4)*16 + (ln&15) within wave
    const int g = ln >> 4;
    const int idxv = (g == 0) ? bi[0] : (g == 1) ? bi[1] : (g == 2) ? bi[2] : bi[3];
    const int tok = w * 64 + ln;

    out[IDX_OFF + (size_t)b * TLEN + t0 + tok] = (float)idxv;

    const float* er   = emb + (size_t)idxv * DIMC;   // fp32 codebook row
    const float* zrow = &zs[tok * 65];
    float* qo = out + (size_t)b * (DIMC * TLEN) + t0 + tok;

    float lsum = 0.f;
    #pragma unroll
    for (int c4 = 0; c4 < DIMC / 4; ++c4) {
        float4 ev = *(const float4*)(er + c4 * 4);
        float z0 = zrow[c4 * 4 + 0], z1 = zrow[c4 * 4 + 1];
        float z2 = zrow[c4 * 4 + 2], z3 = zrow[c4 * 4 + 3];
        float d0 = ev.x - z0, d1 = ev.y - z1, d2 = ev.z - z2, d3 = ev.w - z3;
        qo[(size_t)(c4 * 4 + 0) * TLEN] = z0 + d0;   // z + (q - z), ref rounding
        qo[(size_t)(c4 * 4 + 1) * TLEN] = z1 + d1;
        qo[(size_t)(c4 * 4 + 2) * TLEN] = z2 + d2;
        qo[(size_t)(c4 * 4 + 3) * TLEN] = z3 + d3;
        lsum = fmaf(d0, d0, lsum); lsum = fmaf(d1, d1, lsum);
        lsum = fmaf(d2, d2, lsum); lsum = fmaf(d3, d3, lsum);
    }

    #pragma unroll
    for (int off = 32; off > 0; off >>= 1)
        lsum += __shfl_down(lsum, off, 64);
    if (ln == 0) atomicAdd(lossAcc, lsum);
}

// ---------------------------------------------------------------------------
// Kernel 2: segment-sum binning via LDS accumulator, replica-atomic flush
// grid = NTOK/K2_SPAN = 256 blocks x 256 thr; 1 block/CU (135 KB LDS)
// ---------------------------------------------------------------------------
__global__ __launch_bounds__(256, 1) void vq_bin_kernel(
    const float* __restrict__ z,
    const float* __restrict__ out,    // reads idx at IDX_OFF
    float* __restrict__ cnt,          // [R][KB_NUM]
    float* __restrict__ esum,         // [R][KB_NUM*DIMC]
    int R)
{
    __shared__ float acc[KB_NUM][DIMC + 1];
    __shared__ float scnt[KB_NUM];

    const int tid = threadIdx.x;
    for (int j = tid; j < KB_NUM * (DIMC + 1); j += 256) ((float*)acc)[j] = 0.f;
    for (int j = tid; j < KB_NUM; j += 256) scnt[j] = 0.f;
    __syncthreads();

    const int gt0 = blockIdx.x * K2_SPAN;
    #pragma unroll
    for (int it = 0; it < K2_SPAN / 256; ++it) {
        const int gt = gt0 + it * 256 + tid;
        const int b  = gt >> 12;
        const int t  = gt & (TLEN - 1);
        const int idx = (int)out[IDX_OFF + gt];
        atomicAdd(&scnt[idx], 1.0f);
        const float* zp = z + (size_t)b * (DIMC * TLEN) + t;
        #pragma unroll 4
        for (int c = 0; c < DIMC; ++c) {
            float zv = zp[(size_t)c * TLEN];
            atomicAdd(&acc[idx][c], zv);
        }
    }
    __syncthreads();

    const int r = (int)((unsigned)blockIdx.x % (unsigned)R);
    for (int j = tid; j < KB_NUM * DIMC; j += 256) {
        const int k = j >> 6, c = j & 63;
        float v = acc[k][c];
        if (v != 0.f) atomicAdd(esum + (size_t)r * (KB_NUM * DIMC) + j, v);
    }
    for (int j = tid; j < KB_NUM; j += 256) {
        float v = scnt[j];
        if (v != 0.f) atomicAdd(cnt + (size_t)r * KB_NUM + j, v);
    }
}

// ---------------------------------------------------------------------------
// Kernel 3: stats — new_cluster_size, n_tot, perplexity, loss
// ---------------------------------------------------------------------------
__global__ __launch_bounds__(512) void vq_stats_kernel(
    const float* __restrict__ cluster_size,
    const float* __restrict__ cnt,
    const float* __restrict__ lossAcc,
    float* __restrict__ out,
    float* __restrict__ ntotp,
    int R)
{
    const int k = threadIdx.x;

    float n = 0.f;
    #pragma unroll 4
    for (int r = 0; r < R; ++r) n += cnt[(size_t)r * KB_NUM + k];

    float ncs = cluster_size[k] * DECAY_F + (1.0f - DECAY_F) * n;
    out[NCS_OFF + k] = ncs;

    __shared__ float red[KB_NUM];

    red[k] = ncs;
    __syncthreads();
    for (int s = KB_NUM / 2; s > 0; s >>= 1) {
        if (k < s) red[k] += red[k + s];
        __syncthreads();
    }
    if (k == 0) ntotp[0] = red[0];
    __syncthreads();

    float p = n * (1.0f / (float)NTOK);
    red[k] = p * logf(p + 1e-10f);
    __syncthreads();
    for (int s = KB_NUM / 2; s > 0; s >>= 1) {
        if (k < s) red[k] += red[k + s];
        __syncthreads();
    }
    if (k == 0) {
        out[PLEX_OFF] = expf(-red[0]);
        out[LOSS_OFF] = 0.25f * lossAcc[0] * (1.0f / (float)(BSZ * DIMC * TLEN));
    }
}

// ---------------------------------------------------------------------------
// Kernel 4: embedding update — 512 blocks x 64 threads
// ---------------------------------------------------------------------------
__global__ __launch_bounds__(64) void vq_embed_kernel(
    const float* __restrict__ embed_avg,
    const float* __restrict__ esum,
    const float* __restrict__ ntotp,
    float* __restrict__ out,
    int R)
{
    const int k = blockIdx.x;
    const int c = threadIdx.x;

    float es = 0.f;
    #pragma unroll 4
    for (int r = 0; r < R; ++r)
        es += esum[((size_t)r * KB_NUM + k) * DIMC + c];

    float nea = embed_avg[(size_t)k * DIMC + c] * DECAY_F + (1.0f - DECAY_F) * es;
    out[NEA_OFF + (size_t)k * DIMC + c] = nea;

    float ncs  = out[NCS_OFF + k];
    float ntot = ntotp[0];
    float denom = (ncs + EPS_F) / (ntot + (float)KB_NUM * EPS_F) * ntot;
    out[NEMB_OFF + (size_t)k * DIMC + c] = nea / denom;
}

// ---------------------------------------------------------------------------
extern "C" void kernel_launch(void* const* d_in, const int* in_sizes, int n_in,
                              void* d_out, int out_size, void* d_ws, size_t ws_size,
                              hipStream_t stream)
{
    const float* z            = (const float*)d_in[0];
    const float* emb          = (const float*)d_in[1];
    const float* cluster_size = (const float*)d_in[2];
    const float* embed_avg    = (const float*)d_in[3];
    float* out = (float*)d_out;

    char* ws = (char*)d_ws;
    float*     lossAcc = (float*)ws;                 // 1 f32
    float*     ntotp   = (float*)(ws + 64);          // 1 f32
    float*     enorm   = (float*)(ws + 256);         // 512 f32
    _Float16*  eh      = (_Float16*)(ws + 4096);     // 512*64 f16 = 64 KB
    _Float16*  el      = (_Float16*)(ws + 4096 + 65536);  // 64 KB
    const size_t CNT_OFF = 4096 + 131072;            // 135168
    const size_t perR = (size_t)(KB_NUM + KB_NUM * DIMC) * sizeof(float); // 133120

    int R = 1;
    if (ws_size > CNT_OFF + perR)
        R = (int)((ws_size - CNT_OFF) / perR);
    if (R < 1) R = 1;
    if (R > 16) R = 16;

    float* cnt  = (float*)(ws + CNT_OFF);    // [R][KB_NUM]
    float* esum = cnt + (size_t)R * KB_NUM;  // [R][KB_NUM*DIMC]

    hipMemsetAsync(ws, 0, 4096, stream);                       // lossAcc, ntot
    hipMemsetAsync(ws + CNT_OFF, 0, (size_t)R * perR, stream); // cnt + esum

    vq_prep_e<<<dim3(KB_NUM), dim3(DIMC), 0, stream>>>(emb, eh, el, enorm);

    vq_main_kernel<<<dim3(NTOK / 256), dim3(256), 0, stream>>>(
        z, emb, eh, el, enorm, out, lossAcc);

    vq_bin_kernel<<<dim3(NTOK / K2_SPAN), dim3(256), 0, stream>>>(z, out, cnt, esum, R);

    vq_stats_kernel<<<dim3(1), dim3(512), 0, stream>>>(
        cluster_size, cnt, lossAcc, out, ntotp, R);

    vq_embed_kernel<<<dim3(KB_NUM), dim3(DIMC), 0, stream>>>(
        embed_avg, esum, ntotp, out, R);
}